// Round 10
// baseline (1083.587 us; speedup 1.0000x reference)
//
#include <hip/hip_runtime.h>

typedef _Float16 f16;
typedef __attribute__((ext_vector_type(8))) _Float16 f16x8;
typedef __attribute__((ext_vector_type(4))) _Float16 f16x4;
typedef __attribute__((ext_vector_type(4))) float f32x4;

#define SLICE_H 4326400   // 33800 padded positions * 128 ch (elements)

// ---------------- helpers ----------------

__device__ __forceinline__ void gld_lds16(void* lds, const void* g) {
  // async global->LDS, 16B per lane; LDS dest = wave-uniform base + lane*16
  __builtin_amdgcn_global_load_lds(
      (const __attribute__((address_space(1))) void*)g,
      (__attribute__((address_space(3))) void*)lds, 16, 0, 0);
}

__device__ __forceinline__ float sigf(float v) { return 1.0f / (1.0f + __expf(-v)); }
__device__ __forceinline__ float tanh_fast(float v) { return 2.0f / (1.0f + __expf(-2.0f * v)) - 1.0f; }

// ---------------- weight transforms ----------------

// output-conv weights: [O][I][3][3] -> [tap][O*I] f16 (no permutation)
__global__ __launch_bounds__(256) void kwt(const float* __restrict__ wsrc,
                                           f16* __restrict__ th, int R) {
  int idx = blockIdx.x * 256 + threadIdx.x;
  if (idx >= 9 * R) return;
  int tap = idx / R, r = idx - tap * R;     // r = cout*CIN + ci
  th[idx] = (f16)wsrc[(size_t)r * 9 + tap];
}

// gate weights with gate-interleaved cout permutation:
//   original cout co = gate*128 + hch  (gate: i,f,o,g)
//   new row N = (hch>>6)*256 + ((hch&63)>>4)*64 + gate*16 + (hch&15)
// so that: block z = hch>>6, wave wn = (hch&63)>>4, MFMA frag nf == gate,
// lane&15 == hch low bits -> the 4 gates of one (px,lch) land in one
// thread's acc[mf][0..3][r] -> LSTM computed fully in registers.
__global__ __launch_bounds__(256) void kwtg(const float* __restrict__ wsrc,
                                            f16* __restrict__ th) {
  int idx = blockIdx.x * 256 + threadIdx.x;
  const int R = 512 * 192;
  if (idx >= 9 * R) return;
  int tap = idx / R, rr = idx - tap * R;
  int co = rr / 192, ci = rr - co * 192;
  int gate = co >> 7, hch = co & 127;
  int N = ((hch >> 6) << 8) + (((hch & 63) >> 4) << 6) + (gate << 4) + (hch & 15);
  th[(size_t)tap * R + (size_t)N * 192 + ci] = (f16)wsrc[(size_t)rr * 9 + tap];
}

// ---------------- x slice: NCHW fp32 -> padded NHWC f16 ----------------

__global__ __launch_bounds__(256) void kxform(const float* __restrict__ xt,
                                              f16* __restrict__ xp) {
  int pid = blockIdx.x * 256 + threadIdx.x;          // 2*128*128 pixels
  int b = pid >> 14, y = (pid >> 7) & 127, x = pid & 127;
  const float* src = xt + (size_t)b * 64 * 16384 + (size_t)y * 128 + x;
  size_t doff = ((size_t)((b * 130 + y + 1) * 130 + (x + 1))) * 64;
#pragma unroll
  for (int cc = 0; cc < 8; ++cc) {
    f16x8 vh;
#pragma unroll
    for (int j = 0; j < 8; ++j) vh[j] = (f16)src[(size_t)(cc * 8 + j) * 16384];
    *(f16x8*)(xp + doff + cc * 8) = vh;
  }
}

// ---------------- gate conv + fused LSTM (m201-style 2-phase/tap) ----------
// implicit GEMM M=32768 N=512 K=1728; block: TWO y-rows (256 px) x 256
// permuted couts; 512 threads, 8 waves (2M x 4N), wave tile 128x64
// (acc[8][4]).  Grid 64x2x2 = 256 blocks = exactly 1/CU.
// LDS: A patch [4][132][32] (rows y0..y0+3 padded; halo shared by the two
// output rows, reused over 9 taps) + B ring [3][256][32].
// Per tap, 2 phases of {ds_reads -> barrier -> setprio 16 MFMA -> barrier};
// B prefetched 2 taps ahead, steady-state wait vmcnt(2); full drain only
// at the 6 cig boundaries.  Epilogue: LSTM pointwise in-register.

#define SMEM_G (33792 + 49152)

__global__ __launch_bounds__(512, 2) void kgates(
    const f16* __restrict__ xp, const f16* __restrict__ hp,
    const f16* __restrict__ wg, const float* __restrict__ bg,
    float* __restrict__ cbuf, f16* __restrict__ hslot) {
  extern __shared__ char smem[];
  f16* Ap = (f16*)smem;                    // [4][132][32]
  f16* Br = (f16*)(smem + 33792);          // ring [3][256][32]
  const int tid = threadIdx.x;
  const int lane = tid & 63;
  const int w = tid >> 6;
  const int y0 = blockIdx.x * 2;           // two output rows y0, y0+1
  const int b = blockIdx.y;
  const int z = blockIdx.z;
  const int n0 = z * 256;
  const int wm = w >> 2, wn = w & 3;
  const int chunk = (lane & 3) ^ ((lane >> 3) & 3);

  f32x4 acc[8][4] = {};

  auto stageA = [&](int cig) {             // 4 rows x 132 pos x 32 ch
    const f16* S; int CS, cigl;
    if (cig < 2) { S = xp; CS = 64;  cigl = cig; }
    else         { S = hp; CS = 128; cigl = cig - 2; }
    for (int i = w; i < 36; i += 8) {
      int dyg = i / 9, sub = i - dyg * 9;
      int xp0 = sub * 16;
      const f16* src = S +
          ((size_t)((b * 130 + y0 + dyg) * 130 + xp0 + (lane >> 2))) * CS +
          cigl * 32 + chunk * 8;
      f16* dst = Ap + (dyg * 132 + xp0) * 32;
      if (sub == 8) { if (lane < 16) gld_lds16(dst, src); }
      else gld_lds16(dst, src);
    }
  };
  auto stageB = [&](int j) {               // 2 loads/wave, 16KB slot
    int cig = j / 9, tap = j - cig * 9;
    f16* dst = Br + (j % 3) * 8192;
    for (int i = w; i < 16; i += 8) {
      const f16* src = wg +
          ((size_t)(tap * 512 + n0 + i * 16 + (lane >> 2))) * 192 +
          cig * 32 + chunk * 8;
      gld_lds16(dst + i * 512, src);
    }
  };

  // prologue: A(0) [4-5 loads] + B(0) + B(1) [2 each]; keep B(1) in flight
  stageA(0);
  stageB(0);
  stageB(1);
  asm volatile("s_waitcnt vmcnt(2)" ::: "memory");
  __builtin_amdgcn_s_barrier();

  for (int j = 0; j < 54; ++j) {
    const int cig = j / 9, tap = j - cig * 9;
    const int dy = tap / 3, dx = tap - dy * 3;
    const int q = lane >> 4;
    const f16* Bc = Br + (j % 3) * 8192;
    const f16* Arow = Ap + (wm + dy) * (132 * 32);
    f16x8 af0[4], af1[4], bfr[4];

    // ---- phase 0: frags for mf 0..3 + B tile; prefetch B(j+2)
#pragma unroll
    for (int mf = 0; mf < 4; ++mf) {
      int r = mf * 16 + (lane & 15) + dx;
      af0[mf] = *(const f16x8*)(Arow + r * 32 + ((q ^ ((r >> 1) & 3)) << 3));
    }
#pragma unroll
    for (int nf = 0; nf < 4; ++nf) {
      int n = wn * 64 + nf * 16 + (lane & 15);
      bfr[nf] = *(const f16x8*)(Bc + n * 32 + ((q ^ ((n >> 1) & 3)) << 3));
    }
    if (j + 2 < 54) stageB(j + 2);
    __builtin_amdgcn_s_barrier();
    __builtin_amdgcn_s_setprio(1);
#pragma unroll
    for (int mf = 0; mf < 4; ++mf)
#pragma unroll
      for (int nf = 0; nf < 4; ++nf)
        acc[mf][nf] = __builtin_amdgcn_mfma_f32_16x16x32_f16(af0[mf], bfr[nf], acc[mf][nf], 0, 0, 0);
    __builtin_amdgcn_s_setprio(0);
    __builtin_amdgcn_s_barrier();

    // ---- phase 1: frags for mf 4..7
#pragma unroll
    for (int mf = 0; mf < 4; ++mf) {
      int r = (mf + 4) * 16 + (lane & 15) + dx;
      af1[mf] = *(const f16x8*)(Arow + r * 32 + ((q ^ ((r >> 1) & 3)) << 3));
    }
    __builtin_amdgcn_s_barrier();
    __builtin_amdgcn_s_setprio(1);
#pragma unroll
    for (int mf = 0; mf < 4; ++mf)
#pragma unroll
      for (int nf = 0; nf < 4; ++nf)
        acc[mf + 4][nf] = __builtin_amdgcn_mfma_f32_16x16x32_f16(af1[mf], bfr[nf], acc[mf + 4][nf], 0, 0, 0);
    __builtin_amdgcn_s_setprio(0);

    if (tap == 8) {
      __builtin_amdgcn_s_barrier();        // all waves done reading Ap
      if (cig < 5) stageA(cig + 1);
      asm volatile("s_waitcnt vmcnt(0)" ::: "memory");
      __builtin_amdgcn_s_barrier();
    } else {
      if (j + 2 < 54) asm volatile("s_waitcnt vmcnt(2)" ::: "memory");
      else            asm volatile("s_waitcnt vmcnt(0)" ::: "memory");
      __builtin_amdgcn_s_barrier();
    }
  }

  // fused LSTM epilogue: acc[mf][gate][r]; thread owns (px, lch) pairs of
  // output row y0+wm
  const int hch = z * 64 + wn * 16 + (lane & 15);
  const float bi  = bg[hch];
  const float bf2 = bg[128 + hch];
  const float bo2 = bg[256 + hch];
  const float bg2 = bg[384 + hch];
  const int yr = y0 + wm;
  const size_t pixbase = ((size_t)(b * 128 + yr)) * 128;
  const size_t hbase = ((size_t)((b * 130 + yr + 1) * 130 + 1)) * 128 + hch;
#pragma unroll
  for (int mf = 0; mf < 8; ++mf) {
#pragma unroll
    for (int r = 0; r < 4; ++r) {
      int px = mf * 16 + (lane >> 4) * 4 + r;
      size_t cidx = (pixbase + px) * 128 + hch;
      float co = cbuf[cidx];
      float iv = sigf(acc[mf][0][r] + bi);
      float fv = sigf(acc[mf][1][r] + bf2);
      float ov = sigf(acc[mf][2][r] + bo2);
      float gv = tanh_fast(acc[mf][3][r] + bg2);
      float cv = fv * co + iv * gv;
      cbuf[cidx] = cv;
      hslot[hbase + (size_t)px * 128] = (f16)(ov * tanh_fast(cv));
    }
  }
}

// ---------------- output conv, batched over 4 timesteps: M=131072 N=64 K=1152 ----
// block: 128 px row x 64 couts; 4 waves M-split, wave tile 32x64 (acc[2][4]).
// Counted-vmcnt ring-3 pipeline; steady-state wait vmcnt(1).

#define SMEM_O (25344 + 12288)

__global__ __launch_bounds__(256, 4) void koutconv(
    const f16* __restrict__ hr, int slot0, const f16* __restrict__ wo,
    const float* __restrict__ bo, float* __restrict__ outb) {
  extern __shared__ char smem[];
  f16* Ap = (f16*)smem;                    // [3][132][32]
  f16* Br = (f16*)(smem + 25344);          // ring [3][64][32]
  const int tid = threadIdx.x, lane = tid & 63, w = tid >> 6;
  const int y = blockIdx.x;
  const int b = blockIdx.y;
  const int ts = blockIdx.z;
  const f16* hp = hr + (size_t)((slot0 + ts) % 5) * SLICE_H;
  float* outt = outb + (size_t)ts * 2 * 64 * 16384;
  const int chunk = (lane & 3) ^ ((lane >> 3) & 3);

  f32x4 acc[2][4] = {};

  auto stageA = [&](int cig) {
    for (int i = w; i < 27; i += 4) {
      int dy = i / 9, sub = i - dy * 9;
      int xp0 = sub * 16;
      const f16* src = hp +
          ((size_t)((b * 130 + y + dy) * 130 + xp0 + (lane >> 2))) * 128 +
          cig * 32 + chunk * 8;
      f16* dst = Ap + (dy * 132 + xp0) * 32;
      if (sub == 8) { if (lane < 16) gld_lds16(dst, src); }
      else gld_lds16(dst, src);
    }
  };
  auto stageB = [&](int j, int slot) {     // 1 load/wave
    int cig = j / 9, tap = j - cig * 9;
    const f16* src = wo +
        ((size_t)(tap * 64 + w * 16 + (lane >> 2))) * 128 +
        cig * 32 + chunk * 8;
    gld_lds16(Br + slot * 2048 + w * 512, src);
  };

  stageA(0);
  stageB(0, 0);
  stageB(1, 1);
  asm volatile("s_waitcnt vmcnt(1)" ::: "memory");
  __builtin_amdgcn_s_barrier();

  int sl = 0;
  for (int cig = 0; cig < 4; ++cig) {
    for (int tap = 0; tap < 9; ++tap) {
      const int j = cig * 9 + tap;
      const int dy = tap / 3, dx = tap - dy * 3;
      const int q = lane >> 4;
      const f16* Bc = Br + sl * 2048;
      f16x8 af[2], bfr[4];
#pragma unroll
      for (int mf = 0; mf < 2; ++mf) {
        int r = w * 32 + mf * 16 + (lane & 15) + dx;
        af[mf] = *(const f16x8*)(Ap + (dy * 132 + r) * 32 + ((q ^ ((r >> 1) & 3)) << 3));
      }
#pragma unroll
      for (int nf = 0; nf < 4; ++nf) {
        int n = nf * 16 + (lane & 15);
        bfr[nf] = *(const f16x8*)(Bc + n * 32 + ((q ^ ((n >> 1) & 3)) << 3));
      }
      if (j + 2 < 36) stageB(j + 2, (sl + 2 >= 3) ? sl - 1 : sl + 2);
      __builtin_amdgcn_s_setprio(1);
#pragma unroll
      for (int mf = 0; mf < 2; ++mf)
#pragma unroll
        for (int nf = 0; nf < 4; ++nf)
          acc[mf][nf] = __builtin_amdgcn_mfma_f32_16x16x32_f16(af[mf], bfr[nf], acc[mf][nf], 0, 0, 0);
      __builtin_amdgcn_s_setprio(0);
      if (tap == 8) {
        __builtin_amdgcn_s_barrier();
        if (cig < 3) stageA(cig + 1);
        asm volatile("s_waitcnt vmcnt(0)" ::: "memory");
        __builtin_amdgcn_s_barrier();
      } else {
        if (j + 2 < 36) asm volatile("s_waitcnt vmcnt(1)" ::: "memory");
        else            asm volatile("s_waitcnt vmcnt(0)" ::: "memory");
        __builtin_amdgcn_s_barrier();
      }
      sl = (sl + 1 >= 3) ? 0 : sl + 1;
    }
  }

#pragma unroll
  for (int nf = 0; nf < 4; ++nf) {
    int cout = nf * 16 + (lane & 15);
    float bias = bo[cout];
#pragma unroll
    for (int mf = 0; mf < 2; ++mf) {
      int xbase = w * 32 + mf * 16 + (lane >> 4) * 4;
      f32x4 v = acc[mf][nf];
      v[0] += bias; v[1] += bias; v[2] += bias; v[3] += bias;
      *(f32x4*)(outt + (((size_t)b * 64 + cout) * 128 + y) * 128 + xbase) = v;
    }
  }
}

// ---------------- host ----------------

extern "C" void kernel_launch(void* const* d_in, const int* in_sizes, int n_in,
                              void* d_out, int out_size, void* d_ws, size_t ws_size,
                              hipStream_t stream) {
  const float* x  = (const float*)d_in[0];
  const float* Wg = (const float*)d_in[1];
  const float* bg = (const float*)d_in[2];
  const float* Wo = (const float*)d_in[3];
  const float* bo = (const float*)d_in[4];
  float* out = (float*)d_out;

  char* base = (char*)d_ws;
  size_t off = 0;
  auto carve = [&](size_t bytes) {
    char* p = base + off;
    off += (bytes + 1023) & ~(size_t)1023;
    return p;
  };
  const size_t PADPOS = (size_t)2 * 130 * 130;           // 33800 padded positions
  const size_t xpad_b  = PADPOS * 64 * 2 + 1024;          // f16
  const size_t hring_b = (size_t)5 * SLICE_H * 2 + 1024;  // 5 padded h slices, f16
  const size_t c_b = (size_t)2 * 128 * 128 * 128 * 4;     // fp32 cell state

  f16* xp    = (f16*)carve(xpad_b);
  f16* hr    = (f16*)carve(hring_b);
  float* cbuf = (float*)carve(c_b);
  f16* wg    = (f16*)carve((size_t)9 * 512 * 192 * 2);
  f16* wo    = (f16*)carve((size_t)9 * 64 * 128 * 2);

  // zero state + pad borders once (in-stream: graph-replay deterministic;
  // interiors are fully rewritten every use, borders stay zero)
  hipMemsetAsync(xp, 0, xpad_b, stream);
  hipMemsetAsync(hr, 0, hring_b, stream);
  hipMemsetAsync(cbuf, 0, c_b, stream);

  kwtg<<<(9 * 512 * 192 + 255) / 256, 256, 0, stream>>>(Wg, wg);
  kwt<<<(9 * 64 * 128 + 255) / 256, 256, 0, stream>>>(Wo, wo, 64 * 128);

  for (int t = 0; t < 12; ++t) {
    const float* xt = x + (size_t)t * 2 * 64 * 16384;
    kxform<<<128, 256, 0, stream>>>(xt, xp);
    kgates<<<dim3(64, 2, 2), 512, SMEM_G, stream>>>(
        xp, hr + (size_t)(t % 5) * SLICE_H, wg, bg, cbuf,
        hr + (size_t)((t + 1) % 5) * SLICE_H);
    if ((t & 3) == 3) {
      koutconv<<<dim3(128, 2, 4), 256, SMEM_O, stream>>>(
          hr, (t - 2) % 5, wo, bo, out + (size_t)(t - 3) * 2 * 64 * 16384);
    }
  }
}

// Round 11
// 990.502 us; speedup vs baseline: 1.0940x; 1.0940x over previous
//
#include <hip/hip_runtime.h>

typedef _Float16 f16;
typedef __attribute__((ext_vector_type(8))) _Float16 f16x8;
typedef __attribute__((ext_vector_type(4))) _Float16 f16x4;
typedef __attribute__((ext_vector_type(4))) float f32x4;

#define SLICE_H 4326400   // 33800 padded positions * 128 ch (elements)

// ---------------- helpers ----------------

__device__ __forceinline__ void gld_lds16(void* lds, const void* g) {
  // async global->LDS, 16B per lane; LDS dest = wave-uniform base + lane*16
  __builtin_amdgcn_global_load_lds(
      (const __attribute__((address_space(1))) void*)g,
      (__attribute__((address_space(3))) void*)lds, 16, 0, 0);
}

__device__ __forceinline__ float sigf(float v) { return 1.0f / (1.0f + __expf(-v)); }
__device__ __forceinline__ float tanh_fast(float v) { return 2.0f / (1.0f + __expf(-2.0f * v)) - 1.0f; }

// ---------------- weight transforms ----------------

// output-conv weights: [O][I][3][3] -> [tap][O*I] f16 (no permutation)
__global__ __launch_bounds__(256) void kwt(const float* __restrict__ wsrc,
                                           f16* __restrict__ th, int R) {
  int idx = blockIdx.x * 256 + threadIdx.x;
  if (idx >= 9 * R) return;
  int tap = idx / R, r = idx - tap * R;     // r = cout*CIN + ci
  th[idx] = (f16)wsrc[(size_t)r * 9 + tap];
}

// gate weights with gate-interleaved cout permutation:
//   original cout co = gate*128 + hch  (gate: i,f,o,g)
//   new row N = (hch>>6)*256 + ((hch&63)>>4)*64 + gate*16 + (hch&15)
// so that: block z = hch>>6, wave w = (hch&63)>>4, MFMA frag nf == gate,
// lane&15 == hch low bits -> the 4 gates of one (px,lch) land in one
// thread's acc[mf][0..3][r] -> LSTM computed fully in registers.
__global__ __launch_bounds__(256) void kwtg(const float* __restrict__ wsrc,
                                            f16* __restrict__ th) {
  int idx = blockIdx.x * 256 + threadIdx.x;
  const int R = 512 * 192;
  if (idx >= 9 * R) return;
  int tap = idx / R, rr = idx - tap * R;
  int co = rr / 192, ci = rr - co * 192;
  int gate = co >> 7, hch = co & 127;
  int N = ((hch >> 6) << 8) + (((hch & 63) >> 4) << 6) + (gate << 4) + (hch & 15);
  th[(size_t)tap * R + (size_t)N * 192 + ci] = (f16)wsrc[(size_t)rr * 9 + tap];
}

// ---------------- x slice: NCHW fp32 -> padded NHWC f16 ----------------

__global__ __launch_bounds__(256) void kxform(const float* __restrict__ xt,
                                              f16* __restrict__ xp) {
  int pid = blockIdx.x * 256 + threadIdx.x;          // 2*128*128 pixels
  int b = pid >> 14, y = (pid >> 7) & 127, x = pid & 127;
  const float* src = xt + (size_t)b * 64 * 16384 + (size_t)y * 128 + x;
  size_t doff = ((size_t)((b * 130 + y + 1) * 130 + (x + 1))) * 64;
#pragma unroll
  for (int cc = 0; cc < 8; ++cc) {
    f16x8 vh;
#pragma unroll
    for (int j = 0; j < 8; ++j) vh[j] = (f16)src[(size_t)(cc * 8 + j) * 16384];
    *(f16x8*)(xp + doff + cc * 8) = vh;
  }
}

// ---------------- gate conv + fused LSTM ----------------
// implicit GEMM M=32768 N=512 K=1728; block: one y-row (128 px) x 256
// permuted couts; 4 waves (N-split), wave tile 128x64 (acc[8][4]).
// Counted-vmcnt ring-3 B prefetch (2 taps ahead, steady wait vmcnt(4)),
// issued BEFORE the frag ds_reads (issue-early).  Frag addresses folded:
// swizzle key (r>>1)&3 is mf-independent -> 2 base pointers + immediate
// offsets for all 12 ds_read_b128.  A patch [3][132][32] halo-reused over
// 9 taps, restaged per cig (full drain only at 6 cig boundaries).
// Epilogue: LSTM pointwise in-register; c kept NCHW so c I/O is f32x4.

#define SMEM_G (25344 + 49152)

__global__ __launch_bounds__(256, 2) void kgates(
    const f16* __restrict__ xp, const f16* __restrict__ hp,
    const f16* __restrict__ wg, const float* __restrict__ bg,
    float* __restrict__ cbuf, f16* __restrict__ hslot) {
  extern __shared__ char smem[];
  f16* Ap = (f16*)smem;                    // [3][132][32]
  f16* Br = (f16*)(smem + 25344);          // ring [3][256][32]
  const int tid = threadIdx.x;
  const int lane = tid & 63;
  const int w = tid >> 6;                  // wave = N quadrant
  const int l15 = lane & 15;
  const int q = lane >> 4;
  const int y = blockIdx.x;
  const int b = blockIdx.y;
  const int z = blockIdx.z;
  const int n0 = z * 256;
  const int chunk = (lane & 3) ^ ((lane >> 3) & 3);
  const int bq8 = (q ^ ((l15 >> 1) & 3)) << 3;   // B swizzle: per-thread const

  f32x4 acc[8][4] = {};

  // hoisted per-thread source bases
  const f16* wgthr = wg + (size_t)(n0 + (lane >> 2)) * 192 + chunk * 8 + w * 3072;

  auto stageA = [&](int cig) {
    const f16* S; int CS, cigl;
    if (cig < 2) { S = xp; CS = 64;  cigl = cig; }
    else         { S = hp; CS = 128; cigl = cig - 2; }
    for (int i = w; i < 27; i += 4) {
      int dy = i / 9, sub = i - dy * 9;
      int xp0 = sub * 16;
      const f16* src = S +
          ((size_t)((b * 130 + y + dy) * 130 + xp0 + (lane >> 2))) * CS +
          cigl * 32 + chunk * 8;
      f16* dst = Ap + (dy * 132 + xp0) * 32;
      if (sub == 8) { if (lane < 16) gld_lds16(dst, src); }
      else gld_lds16(dst, src);
    }
  };
  auto stageB = [&](int j) {               // 4 loads/wave
    int cig = j / 9, tap = j - cig * 9;
    f16* dst = Br + (j % 3) * 8192 + w * 512;
    const f16* src = wgthr + (size_t)tap * (512 * 192) + cig * 32;
#pragma unroll
    for (int ii = 0; ii < 4; ++ii)
      gld_lds16(dst + ii * 2048, src + ii * 12288);
  };

  // prologue: A(0) + B(0) + B(1); keep B(1)'s 4 loads in flight
  stageA(0);
  stageB(0);
  stageB(1);
  asm volatile("s_waitcnt vmcnt(4)" ::: "memory");
  __builtin_amdgcn_s_barrier();

  for (int j = 0; j < 54; ++j) {
    const int cig = j / 9, tap = j - cig * 9;
    const int dy = tap / 3, dx = tap - dy * 3;

    if (j + 2 < 54) stageB(j + 2);         // issue-early: loads fly over MFMA

    const f16* Bc = Br + (j % 3) * 8192;
    const int rr = l15 + dx;
    const f16* abase = Ap + dy * (132 * 32) + rr * 32 +
                       ((q ^ ((rr >> 1) & 3)) << 3);
    const f16* bbase = Bc + (w * 64 + l15) * 32 + bq8;
    f16x8 af[8], bfr[4];
#pragma unroll
    for (int mf = 0; mf < 8; ++mf) af[mf] = *(const f16x8*)(abase + mf * 512);
#pragma unroll
    for (int nf = 0; nf < 4; ++nf) bfr[nf] = *(const f16x8*)(bbase + nf * 512);

    __builtin_amdgcn_s_setprio(1);
#pragma unroll
    for (int mf = 0; mf < 8; ++mf)
#pragma unroll
      for (int nf = 0; nf < 4; ++nf)
        acc[mf][nf] = __builtin_amdgcn_mfma_f32_16x16x32_f16(af[mf], bfr[nf], acc[mf][nf], 0, 0, 0);
    __builtin_amdgcn_s_setprio(0);

    if (tap == 8) {
      __builtin_amdgcn_s_barrier();        // all waves done reading Ap
      if (cig < 5) stageA(cig + 1);
      asm volatile("s_waitcnt vmcnt(0)" ::: "memory");
      __builtin_amdgcn_s_barrier();
    } else {
      if (j + 2 < 54) asm volatile("s_waitcnt vmcnt(4)" ::: "memory");
      else            asm volatile("s_waitcnt vmcnt(0)" ::: "memory");
      __builtin_amdgcn_s_barrier();
    }
  }

  // fused LSTM epilogue: acc[mf][gate][r]; c in NCHW -> f32x4 I/O
  const int hch = z * 64 + w * 16 + l15;
  const float bi  = bg[hch];
  const float bf2 = bg[128 + hch];
  const float bo2 = bg[256 + hch];
  const float bg2 = bg[384 + hch];
  float* crow = cbuf + ((size_t)(b * 128 + hch) * 128 + y) * 128;
  f16* hrow = hslot + ((size_t)((b * 130 + y + 1) * 130 + 1)) * 128 + hch;
#pragma unroll
  for (int mf = 0; mf < 8; ++mf) {
    const int px0 = mf * 16 + q * 4;
    f32x4 co = *(const f32x4*)(crow + px0);
    f32x4 cn;
    f16 hv[4];
#pragma unroll
    for (int r = 0; r < 4; ++r) {
      float iv = sigf(acc[mf][0][r] + bi);
      float fv = sigf(acc[mf][1][r] + bf2);
      float ov = sigf(acc[mf][2][r] + bo2);
      float gv = tanh_fast(acc[mf][3][r] + bg2);
      float cv = fv * co[r] + iv * gv;
      cn[r] = cv;
      hv[r] = (f16)(ov * tanh_fast(cv));
    }
    *(f32x4*)(crow + px0) = cn;
#pragma unroll
    for (int r = 0; r < 4; ++r) hrow[(size_t)(px0 + r) * 128] = hv[r];
  }
}

// ---------------- output conv, batched over 4 timesteps: M=131072 N=64 K=1152 ----
// block: 128 px row x 64 couts; 4 waves M-split, wave tile 32x64 (acc[2][4]).
// Counted-vmcnt ring-3 pipeline, issue-early; folded frag addresses.

#define SMEM_O (25344 + 12288)

__global__ __launch_bounds__(256, 4) void koutconv(
    const f16* __restrict__ hr, int slot0, const f16* __restrict__ wo,
    const float* __restrict__ bo, float* __restrict__ outb) {
  extern __shared__ char smem[];
  f16* Ap = (f16*)smem;                    // [3][132][32]
  f16* Br = (f16*)(smem + 25344);          // ring [3][64][32]
  const int tid = threadIdx.x, lane = tid & 63, w = tid >> 6;
  const int l15 = lane & 15, q = lane >> 4;
  const int y = blockIdx.x;
  const int b = blockIdx.y;
  const int ts = blockIdx.z;
  const f16* hp = hr + (size_t)((slot0 + ts) % 5) * SLICE_H;
  float* outt = outb + (size_t)ts * 2 * 64 * 16384;
  const int chunk = (lane & 3) ^ ((lane >> 3) & 3);
  const int bq8 = (q ^ ((l15 >> 1) & 3)) << 3;

  f32x4 acc[2][4] = {};

  const f16* wothr = wo + (size_t)(w * 16 + (lane >> 2)) * 128 + chunk * 8;

  auto stageA = [&](int cig) {
    for (int i = w; i < 27; i += 4) {
      int dy = i / 9, sub = i - dy * 9;
      int xp0 = sub * 16;
      const f16* src = hp +
          ((size_t)((b * 130 + y + dy) * 130 + xp0 + (lane >> 2))) * 128 +
          cig * 32 + chunk * 8;
      f16* dst = Ap + (dy * 132 + xp0) * 32;
      if (sub == 8) { if (lane < 16) gld_lds16(dst, src); }
      else gld_lds16(dst, src);
    }
  };
  auto stageB = [&](int j) {               // 1 load/wave
    int cig = j / 9, tap = j - cig * 9;
    gld_lds16(Br + (j % 3) * 2048 + w * 512,
              wothr + (size_t)tap * (64 * 128) + cig * 32);
  };

  stageA(0);
  stageB(0);
  stageB(1);
  asm volatile("s_waitcnt vmcnt(1)" ::: "memory");
  __builtin_amdgcn_s_barrier();

  for (int cig = 0; cig < 4; ++cig) {
    for (int tap = 0; tap < 9; ++tap) {
      const int j = cig * 9 + tap;
      const int dy = tap / 3, dx = tap - dy * 3;

      if (j + 2 < 36) stageB(j + 2);

      const f16* Bc = Br + (j % 3) * 2048;
      const int rr = l15 + dx;
      const f16* abase = Ap + dy * (132 * 32) + (w * 32 + rr) * 32 +
                         ((q ^ ((rr >> 1) & 3)) << 3);
      const f16* bbase = Bc + l15 * 32 + bq8;
      f16x8 af[2], bfr[4];
#pragma unroll
      for (int mf = 0; mf < 2; ++mf) af[mf] = *(const f16x8*)(abase + mf * 512);
#pragma unroll
      for (int nf = 0; nf < 4; ++nf) bfr[nf] = *(const f16x8*)(bbase + nf * 512);

      __builtin_amdgcn_s_setprio(1);
#pragma unroll
      for (int mf = 0; mf < 2; ++mf)
#pragma unroll
        for (int nf = 0; nf < 4; ++nf)
          acc[mf][nf] = __builtin_amdgcn_mfma_f32_16x16x32_f16(af[mf], bfr[nf], acc[mf][nf], 0, 0, 0);
      __builtin_amdgcn_s_setprio(0);

      if (tap == 8) {
        __builtin_amdgcn_s_barrier();
        if (cig < 3) stageA(cig + 1);
        asm volatile("s_waitcnt vmcnt(0)" ::: "memory");
        __builtin_amdgcn_s_barrier();
      } else {
        if (j + 2 < 36) asm volatile("s_waitcnt vmcnt(1)" ::: "memory");
        else            asm volatile("s_waitcnt vmcnt(0)" ::: "memory");
        __builtin_amdgcn_s_barrier();
      }
    }
  }

#pragma unroll
  for (int nf = 0; nf < 4; ++nf) {
    int cout = nf * 16 + l15;
    float bias = bo[cout];
#pragma unroll
    for (int mf = 0; mf < 2; ++mf) {
      int xbase = w * 32 + mf * 16 + q * 4;
      f32x4 v = acc[mf][nf];
      v[0] += bias; v[1] += bias; v[2] += bias; v[3] += bias;
      *(f32x4*)(outt + (((size_t)b * 64 + cout) * 128 + y) * 128 + xbase) = v;
    }
  }
}

// ---------------- host ----------------

extern "C" void kernel_launch(void* const* d_in, const int* in_sizes, int n_in,
                              void* d_out, int out_size, void* d_ws, size_t ws_size,
                              hipStream_t stream) {
  const float* x  = (const float*)d_in[0];
  const float* Wg = (const float*)d_in[1];
  const float* bg = (const float*)d_in[2];
  const float* Wo = (const float*)d_in[3];
  const float* bo = (const float*)d_in[4];
  float* out = (float*)d_out;

  char* base = (char*)d_ws;
  size_t off = 0;
  auto carve = [&](size_t bytes) {
    char* p = base + off;
    off += (bytes + 1023) & ~(size_t)1023;
    return p;
  };
  const size_t PADPOS = (size_t)2 * 130 * 130;           // 33800 padded positions
  const size_t xpad_b  = PADPOS * 64 * 2 + 1024;          // f16
  const size_t hring_b = (size_t)5 * SLICE_H * 2 + 1024;  // 5 padded h slices, f16
  const size_t c_b = (size_t)2 * 128 * 128 * 128 * 4;     // fp32 cell state (NCHW)

  f16* xp    = (f16*)carve(xpad_b);
  f16* hr    = (f16*)carve(hring_b);
  float* cbuf = (float*)carve(c_b);
  f16* wg    = (f16*)carve((size_t)9 * 512 * 192 * 2);
  f16* wo    = (f16*)carve((size_t)9 * 64 * 128 * 2);

  // zero state + pad borders once (in-stream: graph-replay deterministic;
  // interiors are fully rewritten every use, borders stay zero)
  hipMemsetAsync(xp, 0, xpad_b, stream);
  hipMemsetAsync(hr, 0, hring_b, stream);
  hipMemsetAsync(cbuf, 0, c_b, stream);

  kwtg<<<(9 * 512 * 192 + 255) / 256, 256, 0, stream>>>(Wg, wg);
  kwt<<<(9 * 64 * 128 + 255) / 256, 256, 0, stream>>>(Wo, wo, 64 * 128);

  for (int t = 0; t < 12; ++t) {
    const float* xt = x + (size_t)t * 2 * 64 * 16384;
    kxform<<<128, 256, 0, stream>>>(xt, xp);
    kgates<<<dim3(128, 2, 2), 256, SMEM_G, stream>>>(
        xp, hr + (size_t)(t % 5) * SLICE_H, wg, bg, cbuf,
        hr + (size_t)((t + 1) % 5) * SLICE_H);
    if ((t & 3) == 3) {
      koutconv<<<dim3(128, 2, 4), 256, SMEM_O, stream>>>(
          hr, (t - 2) % 5, wo, bo, out + (size_t)(t - 3) * 2 * 64 * 16384);
    }
  }
}